// Round 1
// baseline (422.595 us; speedup 1.0000x reference)
//
#include <hip/hip_runtime.h>
#include <math.h>

#define NB 48
#define NT 4096
#define ND 256
#define NS 10
#define BLK 455

// ---------------------------------------------------------------------------
// Kernel A: block max.  q[b,s,d] = max over chunk rows (zero-pad participates
// for the last chunk).  One block per (b,s); 256 threads = 64 float4-cols x 4
// row-subsets.
// ---------------------------------------------------------------------------
__global__ __launch_bounds__(256) void kmax(const float* __restrict__ x,
                                            float* __restrict__ q) {
    const int bs = blockIdx.x;            // 0..479
    const int b = bs / NS, s = bs % NS;
    const int g  = threadIdx.x & 63;      // float4 column group
    const int rs = threadIdx.x >> 6;      // row subset 0..3
    const long base = ((long)b * NT + (long)s * BLK) * ND;
    const int nrows = min(BLK, NT - s * BLK);   // 455 except 1 for s==9

    float4 m;
    if (nrows < BLK) m = make_float4(0.f, 0.f, 0.f, 0.f);   // zero pads in max
    else             m = make_float4(-INFINITY, -INFINITY, -INFINITY, -INFINITY);

    for (int r = rs; r < nrows; r += 4) {
        const float4 v = *reinterpret_cast<const float4*>(x + base + (long)r * ND + g * 4);
        m.x = fmaxf(m.x, v.x); m.y = fmaxf(m.y, v.y);
        m.z = fmaxf(m.z, v.z); m.w = fmaxf(m.w, v.w);
    }

    __shared__ float4 red[4][64];
    red[rs][g] = m;
    __syncthreads();
    if (rs == 0) {
        float4 a = red[0][g];
        #pragma unroll
        for (int k = 1; k < 4; ++k) {
            float4 o = red[k][g];
            a.x = fmaxf(a.x, o.x); a.y = fmaxf(a.y, o.y);
            a.z = fmaxf(a.z, o.z); a.w = fmaxf(a.w, o.w);
        }
        *reinterpret_cast<float4*>(q + (long)bs * ND + g * 4) = a;
    }
}

// ---------------------------------------------------------------------------
// Kernel B: q_block = softmax(q q^T / 16) q  per batch.  Tiny (10x10).
// ---------------------------------------------------------------------------
__global__ __launch_bounds__(256) void kqblock(const float* __restrict__ q,
                                               float* __restrict__ qb) {
    const int b = blockIdx.x;
    const int tid = threadIdx.x;
    __shared__ float sq[NS][ND];
    __shared__ float sp[NS][NS];

    for (int i = tid; i < NS * ND; i += 256)
        sq[i / ND][i % ND] = q[(long)b * NS * ND + i];
    __syncthreads();

    if (tid < NS * NS) {
        const int i = tid / NS, j = tid % NS;
        float acc = 0.f;
        for (int d = 0; d < ND; ++d) acc += sq[i][d] * sq[j][d];
        sp[i][j] = acc * 0.0625f;           // 1/sqrt(256)
    }
    __syncthreads();

    if (tid < NS) {
        float m = -INFINITY;
        for (int j = 0; j < NS; ++j) m = fmaxf(m, sp[tid][j]);
        float sum = 0.f;
        for (int j = 0; j < NS; ++j) { float e = expf(sp[tid][j] - m); sp[tid][j] = e; sum += e; }
        const float inv = 1.f / sum;
        for (int j = 0; j < NS; ++j) sp[tid][j] *= inv;
    }
    __syncthreads();

    for (int i = 0; i < NS; ++i) {
        float acc = 0.f;
        #pragma unroll
        for (int j = 0; j < NS; ++j) acc += sp[i][j] * sq[j][tid];
        qb[((long)b * NS + i) * ND + tid] = acc;
    }
}

// ---------------------------------------------------------------------------
// Kernel C: q_step[b,s,:] = softmax(q_block[b,s,:] . chunk^T / 16) @ chunk.
// Pad rows of the last chunk contribute score 0 / value 0: denominator gets
// npad * exp(-max) analytically.
// One block per (b,s); 4 waves; pass1 = wave-per-row dot + shuffle reduce,
// pass2 = float4-column weighted accumulation.
// ---------------------------------------------------------------------------
__global__ __launch_bounds__(256) void kstep(const float* __restrict__ x,
                                             const float* __restrict__ qb,
                                             float* __restrict__ qs) {
    const int bs = blockIdx.x;
    const int b = bs / NS, s = bs % NS;
    const int tid  = threadIdx.x;
    const int lane = tid & 63;
    const int w    = tid >> 6;            // wave 0..3
    const long base = ((long)b * NT + (long)s * BLK) * ND;
    const int nrows = min(BLK, NT - s * BLK);
    const int npad  = BLK - nrows;

    const float4 qb4 = *reinterpret_cast<const float4*>(qb + (long)bs * ND + lane * 4);

    __shared__ float sc[BLK];
    __shared__ float rbuf[256];

    // pass 1: scores
    for (int r = w; r < nrows; r += 4) {
        const float4 v = *reinterpret_cast<const float4*>(x + base + (long)r * ND + lane * 4);
        float p = v.x * qb4.x + v.y * qb4.y + v.z * qb4.z + v.w * qb4.w;
        #pragma unroll
        for (int o = 32; o; o >>= 1) p += __shfl_xor(p, o);
        if (lane == 0) sc[r] = p * 0.0625f;
    }
    __syncthreads();

    // block max
    float m = (npad > 0) ? 0.f : -INFINITY;
    for (int r = tid; r < nrows; r += 256) m = fmaxf(m, sc[r]);
    rbuf[tid] = m;
    __syncthreads();
    for (int o = 128; o; o >>= 1) {
        if (tid < o) rbuf[tid] = fmaxf(rbuf[tid], rbuf[tid + o]);
        __syncthreads();
    }
    m = rbuf[0];
    __syncthreads();

    // exp + sum
    float sum = 0.f;
    for (int r = tid; r < nrows; r += 256) {
        const float e = expf(sc[r] - m);
        sc[r] = e;
        sum += e;
    }
    rbuf[tid] = sum;
    __syncthreads();
    for (int o = 128; o; o >>= 1) {
        if (tid < o) rbuf[tid] += rbuf[tid + o];
        __syncthreads();
    }
    const float denom = rbuf[0] + (float)npad * expf(-m);

    // pass 2: weighted accumulation, float4 column g, row subset w
    float4 acc = make_float4(0.f, 0.f, 0.f, 0.f);
    for (int r = w; r < nrows; r += 4) {
        const float4 v = *reinterpret_cast<const float4*>(x + base + (long)r * ND + lane * 4);
        const float p = sc[r];
        acc.x += p * v.x; acc.y += p * v.y;
        acc.z += p * v.z; acc.w += p * v.w;
    }
    __shared__ float4 r4[4][64];
    r4[w][lane] = acc;
    __syncthreads();
    if (w == 0) {
        float4 a = r4[0][lane];
        #pragma unroll
        for (int k = 1; k < 4; ++k) {
            float4 o = r4[k][lane];
            a.x += o.x; a.y += o.y; a.z += o.z; a.w += o.w;
        }
        const float inv = 1.f / denom;
        a.x *= inv; a.y *= inv; a.z *= inv; a.w *= inv;
        *reinterpret_cast<float4*>(qs + (long)bs * ND + lane * 4) = a;
    }
}

// ---------------------------------------------------------------------------
// Kernel D: out[bs,d] = bias[d] + sum_f [qb|qs][f] * W[d,f]   (W: [256][512])
// ---------------------------------------------------------------------------
__global__ __launch_bounds__(256) void kout(const float* __restrict__ qb,
                                            const float* __restrict__ qs,
                                            const float* __restrict__ Wf,
                                            const float* __restrict__ bf,
                                            float* __restrict__ out) {
    const int bs = blockIdx.x;
    const int tid = threadIdx.x;
    __shared__ float f[2 * ND];
    f[tid]      = qb[(long)bs * ND + tid];
    f[ND + tid] = qs[(long)bs * ND + tid];
    __syncthreads();

    const float* wr = Wf + (long)tid * 2 * ND;
    float acc = bf[tid];
    for (int k = 0; k < 2 * ND; k += 4) {
        const float4 w4 = *reinterpret_cast<const float4*>(wr + k);
        acc += f[k] * w4.x + f[k + 1] * w4.y + f[k + 2] * w4.z + f[k + 3] * w4.w;
    }
    out[(long)bs * ND + tid] = acc;
}

extern "C" void kernel_launch(void* const* d_in, const int* in_sizes, int n_in,
                              void* d_out, int out_size, void* d_ws, size_t ws_size,
                              hipStream_t stream) {
    const float* x  = (const float*)d_in[0];
    const float* Wf = (const float*)d_in[1];
    const float* bf = (const float*)d_in[2];
    float* out = (float*)d_out;

    float* q  = (float*)d_ws;                 // [48*10*256]
    float* qb = q  + NB * NS * ND;
    float* qs = qb + NB * NS * ND;

    kmax  <<<NB * NS, 256, 0, stream>>>(x, q);
    kqblock<<<NB,      256, 0, stream>>>(q, qb);
    kstep <<<NB * NS, 256, 0, stream>>>(x, qb, qs);
    kout  <<<NB * NS, 256, 0, stream>>>(qb, qs, Wf, bf, out);
}

// Round 6
// 350.566 us; speedup vs baseline: 1.2055x; 1.2055x over previous
//
#include <hip/hip_runtime.h>
#include <math.h>

#define NB 48
#define NT 4096
#define ND 256
#define NS 10
#define BLK 455
#define NP 4      // parts per chunk
#define RPP 114   // rows per part (last part has 113)

// ---------------------------------------------------------------------------
// K1: partial block max over a quarter-chunk.  Grid = 480*4.
// Zero-pad rows (only chunk s==9) participate in the max at part level.
// ---------------------------------------------------------------------------
__global__ __launch_bounds__(256) void kmaxp(const float* __restrict__ x,
                                             float* __restrict__ qpart) {
    const int bsp = blockIdx.x;           // (b*NS+s)*4 + p
    const int p  = bsp & 3;
    const int bs = bsp >> 2;
    const int b = bs / NS, s = bs % NS;
    const int start = p * RPP;
    const int len   = min(BLK - start, RPP);
    const int nrows = min(BLK, NT - s * BLK);          // 455, or 1 for s==9
    const int nreal = max(0, min(nrows - start, len));
    const int npad  = len - nreal;
    const int g = threadIdx.x & 63;       // float4 column
    const int w = threadIdx.x >> 6;       // wave = row phase
    const long base = ((long)b * NT + (long)s * BLK + start) * ND;

    float4 m = (npad > 0) ? make_float4(0.f, 0.f, 0.f, 0.f)
                          : make_float4(-INFINITY, -INFINITY, -INFINITY, -INFINITY);
    for (int r = w; r < nreal; r += 4) {
        const float4 v = *reinterpret_cast<const float4*>(x + base + (long)r * ND + g * 4);
        m.x = fmaxf(m.x, v.x); m.y = fmaxf(m.y, v.y);
        m.z = fmaxf(m.z, v.z); m.w = fmaxf(m.w, v.w);
    }

    __shared__ float4 red[4][64];
    red[w][g] = m;
    __syncthreads();
    if (w == 0) {
        float4 a = red[0][g];
        #pragma unroll
        for (int k = 1; k < 4; ++k) {
            const float4 o = red[k][g];
            a.x = fmaxf(a.x, o.x); a.y = fmaxf(a.y, o.y);
            a.z = fmaxf(a.z, o.z); a.w = fmaxf(a.w, o.w);
        }
        *reinterpret_cast<float4*>(qpart + (long)bsp * ND + g * 4) = a;
    }
}

// ---------------------------------------------------------------------------
// K2: merge 4 max-partials -> q, then tiny 10x10 self-attention -> qb.
// ---------------------------------------------------------------------------
__global__ __launch_bounds__(256) void kqblock(const float* __restrict__ qpart,
                                               float* __restrict__ qb) {
    const int b = blockIdx.x;
    const int tid = threadIdx.x;
    __shared__ float sq[NS][ND];
    __shared__ float sp[NS][NS];

    for (int i = tid; i < NS * ND; i += 256) {
        const int st = i / ND, d = i % ND;
        const long base = ((long)(b * NS + st) * NP) * ND + d;
        float v = qpart[base];
        #pragma unroll
        for (int p = 1; p < NP; ++p) v = fmaxf(v, qpart[base + (long)p * ND]);
        sq[st][d] = v;
    }
    __syncthreads();

    if (tid < NS * NS) {
        const int i = tid / NS, j = tid % NS;
        float acc = 0.f;
        for (int d = 0; d < ND; ++d) acc += sq[i][d] * sq[j][d];
        sp[i][j] = acc * 0.0625f;          // 1/sqrt(256)
    }
    __syncthreads();

    if (tid < NS) {
        float m = -INFINITY;
        for (int j = 0; j < NS; ++j) m = fmaxf(m, sp[tid][j]);
        float sum = 0.f;
        for (int j = 0; j < NS; ++j) { const float e = expf(sp[tid][j] - m); sp[tid][j] = e; sum += e; }
        const float inv = 1.f / sum;
        for (int j = 0; j < NS; ++j) sp[tid][j] *= inv;
    }
    __syncthreads();

    for (int i = 0; i < NS; ++i) {
        float acc = 0.f;
        #pragma unroll
        for (int j = 0; j < NS; ++j) acc += sp[i][j] * sq[j][tid];
        qb[((long)b * NS + i) * ND + tid] = acc;
    }
}

// ---------------------------------------------------------------------------
// K3: single-pass online-softmax attention partial over a quarter-chunk.
// Grid = 480*4.  Each wave keeps running (m, l, acc[4/lane]); waves merged in
// LDS; pad rows folded in analytically (score 0, value 0).
// ---------------------------------------------------------------------------
__global__ __launch_bounds__(256) void kstepp(const float* __restrict__ x,
                                              const float* __restrict__ qb,
                                              float* __restrict__ mpart,
                                              float* __restrict__ lpart,
                                              float* __restrict__ accpart) {
    const int bsp = blockIdx.x;
    const int p  = bsp & 3;
    const int bs = bsp >> 2;
    const int b = bs / NS, s = bs % NS;
    const int start = p * RPP;
    const int len   = min(BLK - start, RPP);
    const int nrows = min(BLK, NT - s * BLK);
    const int nreal = max(0, min(nrows - start, len));
    const int npad  = len - nreal;
    const int lane = threadIdx.x & 63;
    const int w    = threadIdx.x >> 6;
    const long base = ((long)b * NT + (long)s * BLK + start) * ND;

    const float4 qb4 = *reinterpret_cast<const float4*>(qb + (long)bs * ND + lane * 4);

    float m = -INFINITY, l = 0.f;
    float4 acc = make_float4(0.f, 0.f, 0.f, 0.f);

    for (int r = w; r < nreal; r += 4) {
        const float4 v = *reinterpret_cast<const float4*>(x + base + (long)r * ND + lane * 4);
        float sc = v.x * qb4.x + v.y * qb4.y + v.z * qb4.z + v.w * qb4.w;
        #pragma unroll
        for (int o = 32; o; o >>= 1) sc += __shfl_xor(sc, o);
        sc *= 0.0625f;
        if (sc > m) {                       // uniform branch (sc same in wave)
            const float g = expf(m - sc);   // expf(-inf)=0 on first row
            l *= g; acc.x *= g; acc.y *= g; acc.z *= g; acc.w *= g;
            m = sc;
        }
        const float e = expf(sc - m);
        l += e;
        acc.x += e * v.x; acc.y += e * v.y;
        acc.z += e * v.z; acc.w += e * v.w;
    }

    __shared__ float  sm[4], sl[4];
    __shared__ float4 sacc[4][64];
    if (lane == 0) { sm[w] = m; sl[w] = l; }
    sacc[w][lane] = acc;
    __syncthreads();

    if (w == 0) {
        float mp = (npad > 0) ? 0.f : -INFINITY;
        #pragma unroll
        for (int k = 0; k < 4; ++k) mp = fmaxf(mp, sm[k]);
        float lf = (float)npad * expf(-mp);
        float4 af = make_float4(0.f, 0.f, 0.f, 0.f);
        #pragma unroll
        for (int k = 0; k < 4; ++k) {
            const float g = expf(sm[k] - mp);   // 0 for empty waves
            lf += sl[k] * g;
            const float4 o = sacc[k][lane];
            af.x += o.x * g; af.y += o.y * g;
            af.z += o.z * g; af.w += o.w * g;
        }
        if (lane == 0) { mpart[bsp] = mp; lpart[bsp] = lf; }
        *reinterpret_cast<float4*>(accpart + (long)bsp * ND + lane * 4) = af;
    }
}

// ---------------------------------------------------------------------------
// K4: merge 4 flash partials -> qs, then out = W @ [qb|qs] + bias.
// ---------------------------------------------------------------------------
__global__ __launch_bounds__(256) void kfinal(const float* __restrict__ qb,
                                              const float* __restrict__ mpart,
                                              const float* __restrict__ lpart,
                                              const float* __restrict__ accpart,
                                              const float* __restrict__ Wf,
                                              const float* __restrict__ bf,
                                              float* __restrict__ out) {
    const int bs = blockIdx.x;
    const int d = threadIdx.x;

    const float m0 = mpart[bs * NP + 0], m1 = mpart[bs * NP + 1];
    const float m2 = mpart[bs * NP + 2], m3 = mpart[bs * NP + 3];
    const float mm = fmaxf(fmaxf(m0, m1), fmaxf(m2, m3));
    const float s0 = expf(m0 - mm), s1 = expf(m1 - mm);
    const float s2 = expf(m2 - mm), s3 = expf(m3 - mm);
    const float l = lpart[bs * NP + 0] * s0 + lpart[bs * NP + 1] * s1
                  + lpart[bs * NP + 2] * s2 + lpart[bs * NP + 3] * s3;
    const float a = accpart[((long)bs * NP + 0) * ND + d] * s0
                  + accpart[((long)bs * NP + 1) * ND + d] * s1
                  + accpart[((long)bs * NP + 2) * ND + d] * s2
                  + accpart[((long)bs * NP + 3) * ND + d] * s3;
    const float qs = a / l;

    __shared__ float f[2 * ND];
    f[d]      = qb[(long)bs * ND + d];
    f[ND + d] = qs;
    __syncthreads();

    const float* wr = Wf + (long)d * 2 * ND;
    float acc = bf[d];
    for (int k = 0; k < 2 * ND; k += 4) {
        const float4 w4 = *reinterpret_cast<const float4*>(wr + k);
        acc += f[k] * w4.x + f[k + 1] * w4.y + f[k + 2] * w4.z + f[k + 3] * w4.w;
    }
    out[(long)bs * ND + d] = acc;
}

extern "C" void kernel_launch(void* const* d_in, const int* in_sizes, int n_in,
                              void* d_out, int out_size, void* d_ws, size_t ws_size,
                              hipStream_t stream) {
    const float* x  = (const float*)d_in[0];
    const float* Wf = (const float*)d_in[1];
    const float* bf = (const float*)d_in[2];
    float* out = (float*)d_out;

    float* qpart   = (float*)d_ws;                         // [480*4*256]
    float* accpart = qpart + NB * NS * NP * ND;            // [480*4*256]
    float* qb      = accpart + NB * NS * NP * ND;          // [480*256]
    float* mpart   = qb + NB * NS * ND;                    // [480*4]
    float* lpart   = mpart + NB * NS * NP;                 // [480*4]

    kmaxp  <<<NB * NS * NP, 256, 0, stream>>>(x, qpart);
    kqblock<<<NB,           256, 0, stream>>>(qpart, qb);
    kstepp <<<NB * NS * NP, 256, 0, stream>>>(x, qb, mpart, lpart, accpart);
    kfinal <<<NB * NS,      256, 0, stream>>>(qb, mpart, lpart, accpart, Wf, bf, out);
}